// Round 1
// baseline (464.506 us; speedup 1.0000x reference)
//
#include <hip/hip_runtime.h>
#include <hip/hip_bf16.h>

// Problem constants (from setup_inputs): x[B=32, N=8192, F=256] fp32, k=1024.
#define B_DIM 32
#define N_DIM 8192
#define F_DIM 256
#define K_DIM 1024
#define SORT_THREADS 1024

// Monotonic float32 -> uint32 transform (total order, NaN-free inputs).
__device__ __forceinline__ unsigned int f32_ord(float v) {
    unsigned int u = __float_as_uint(v);
    return (u & 0x80000000u) ? ~u : (u | 0x80000000u);
}

// One block per batch. Full bitonic sort (descending) of 8192 64-bit keys
// in LDS. Key = (ord(value) << 32) | (N-1-idx): descending key order ==
// descending value, ties broken by smaller idx first (lax.top_k semantics).
__global__ __launch_bounds__(SORT_THREADS)
void topk_sort_kernel(const float* __restrict__ x, int* __restrict__ idx_out) {
    __shared__ unsigned long long keys[N_DIM];  // 64 KB

    const int b = blockIdx.x;
    const float* xb = x + (size_t)b * N_DIM * F_DIM;

    // Load last-feature column, build keys.
    for (int t = threadIdx.x; t < N_DIM; t += SORT_THREADS) {
        float v = xb[(size_t)t * F_DIM + (F_DIM - 1)];
        unsigned long long key =
            ((unsigned long long)f32_ord(v) << 32) |
            (unsigned int)(N_DIM - 1 - t);
        keys[t] = key;
    }

    // Bitonic sort, descending overall.
    for (unsigned int kk = 2; kk <= N_DIM; kk <<= 1) {
        for (unsigned int jj = kk >> 1; jj > 0; jj >>= 1) {
            __syncthreads();
            for (unsigned int t = threadIdx.x; t < N_DIM; t += SORT_THREADS) {
                unsigned int ixj = t ^ jj;
                if (ixj > t) {
                    unsigned long long a = keys[t];
                    unsigned long long c = keys[ixj];
                    bool desc = ((t & kk) == 0);
                    // descending segment: want a >= c; ascending: a <= c
                    if (desc ? (a < c) : (a > c)) {
                        keys[t]   = c;
                        keys[ixj] = a;
                    }
                }
            }
        }
    }
    __syncthreads();

    // Emit top-K indices (threads 0..K-1, exactly one each).
    if (threadIdx.x < K_DIM) {
        unsigned int low = (unsigned int)(keys[threadIdx.x] & 0xFFFFFFFFu);
        idx_out[b * K_DIM + threadIdx.x] = (int)(N_DIM - 1 - low);
    }
}

// Gather: out[b, j, :] = x[b, idx[b*K + j], :].
// One float4 per thread; each 64-lane wave covers exactly one 1 KB row.
__global__ __launch_bounds__(256)
void gather_rows_kernel(const float* __restrict__ x,
                        const int* __restrict__ idx,
                        float* __restrict__ out) {
    size_t gid = (size_t)blockIdx.x * blockDim.x + threadIdx.x; // per float4
    int f4       = (int)(gid & (F_DIM / 4 - 1));   // 0..63
    size_t row   = gid >> 6;                       // b*K + j
    int b        = (int)(row >> 10);               // / K_DIM
    int src      = idx[row];                       // wave-uniform -> broadcast

    const float4* src_ptr =
        (const float4*)(x + ((size_t)b * N_DIM + (size_t)src) * F_DIM) + f4;
    ((float4*)out)[gid] = *src_ptr;
}

extern "C" void kernel_launch(void* const* d_in, const int* in_sizes, int n_in,
                              void* d_out, int out_size, void* d_ws, size_t ws_size,
                              hipStream_t stream) {
    const float* x = (const float*)d_in[0];
    float* out = (float*)d_out;
    int* idx_ws = (int*)d_ws;  // B*K ints = 128 KB

    topk_sort_kernel<<<B_DIM, SORT_THREADS, 0, stream>>>(x, idx_ws);

    const size_t total_f4 = (size_t)B_DIM * K_DIM * F_DIM / 4;  // 2,097,152
    gather_rows_kernel<<<(int)(total_f4 / 256), 256, 0, stream>>>(x, idx_ws, out);
}

// Round 2
// 370.914 us; speedup vs baseline: 1.2523x; 1.2523x over previous
//
#include <hip/hip_runtime.h>
#include <hip/hip_bf16.h>

// Problem constants (from setup_inputs): x[B=32, N=8192, F=256] fp32, k=1024.
#define B_DIM 32
#define N_DIM 8192
#define F_DIM 256
#define K_DIM 1024
#define RUNS_PER_B 8          // N / K
#define RUN_LEN 1024          // == K_DIM

// Monotonic float32 -> uint32 transform (total order; inputs are normals, no NaN).
__device__ __forceinline__ unsigned int f32_ord(float v) {
    unsigned int u = __float_as_uint(v);
    return (u & 0x80000000u) ? ~u : (u | 0x80000000u);
}

// ---------------------------------------------------------------------------
// Phase 1: B*8 blocks. Each block sorts one 1024-row chunk of the key column
// descending in LDS and writes the sorted u64 run to ws.
// Key = (ord(value) << 32) | (N-1-row): u64-desc == value-desc, ties -> lowest
// row index first (lax.top_k semantics).
// ---------------------------------------------------------------------------
__global__ __launch_bounds__(256)
void sort_runs_kernel(const float* __restrict__ x,
                      unsigned long long* __restrict__ runs) {
    __shared__ unsigned long long keys[RUN_LEN];  // 8 KB

    const int blk = blockIdx.x;       // b * 8 + c
    const int b   = blk >> 3;
    const int c   = blk & 7;
    const float* xb = x + (size_t)b * N_DIM * F_DIM;
    const int base = c * RUN_LEN;

    for (int i = threadIdx.x; i < RUN_LEN; i += 256) {
        int row = base + i;
        float v = xb[(size_t)row * F_DIM + (F_DIM - 1)];
        keys[i] = ((unsigned long long)f32_ord(v) << 32) |
                  (unsigned int)(N_DIM - 1 - row);
    }
    __syncthreads();

    // Bitonic sort (descending), direct pair indexing -> no divergence.
    for (unsigned int kk = 2; kk <= RUN_LEN; kk <<= 1) {
        for (unsigned int jj = kk >> 1; jj > 0; jj >>= 1) {
            for (unsigned int p = threadIdx.x; p < RUN_LEN / 2; p += 256) {
                unsigned int i = ((p & ~(jj - 1)) << 1) | (p & (jj - 1));
                unsigned int j = i | jj;
                unsigned long long a  = keys[i];
                unsigned long long bb = keys[j];
                bool desc = ((i & kk) == 0);
                if (desc ? (a < bb) : (a > bb)) {
                    keys[i] = bb;
                    keys[j] = a;
                }
            }
            __syncthreads();
        }
    }

    unsigned long long* r = runs + (size_t)blk * RUN_LEN;
    for (int i = threadIdx.x; i < RUN_LEN; i += 256) r[i] = keys[i];
}

// ---------------------------------------------------------------------------
// Phase 2: one block per batch. Fold 7 sorted runs into the running top-1024:
//   C[i] = max(A[i], B[K-1-i])  -- exact top-K multiset of A∪B, bitonic
//   then 10-pass bitonic merge -> sorted descending.
// ---------------------------------------------------------------------------
__global__ __launch_bounds__(256)
void merge_topk_kernel(const unsigned long long* __restrict__ runs,
                       int* __restrict__ idx_out) {
    __shared__ unsigned long long A[K_DIM];   // running top-K (sorted desc)
    __shared__ unsigned long long Bv[K_DIM];  // incoming run

    const int b = blockIdx.x;
    const unsigned long long* rb = runs + (size_t)b * N_DIM;

    for (int i = threadIdx.x; i < K_DIM; i += 256) A[i] = rb[i];

    for (int r = 1; r < RUNS_PER_B; ++r) {
        for (int i = threadIdx.x; i < K_DIM; i += 256) Bv[i] = rb[r * K_DIM + i];
        __syncthreads();

        // top-K of union; result is bitonic in A
        for (int i = threadIdx.x; i < K_DIM; i += 256) {
            unsigned long long m = Bv[K_DIM - 1 - i];
            if (m > A[i]) A[i] = m;
        }
        __syncthreads();

        // bitonic merge, descending
        for (unsigned int jj = K_DIM / 2; jj > 0; jj >>= 1) {
            for (unsigned int p = threadIdx.x; p < K_DIM / 2; p += 256) {
                unsigned int i = ((p & ~(jj - 1)) << 1) | (p & (jj - 1));
                unsigned int j = i | jj;
                unsigned long long a  = A[i];
                unsigned long long cc = A[j];
                if (a < cc) { A[i] = cc; A[j] = a; }
            }
            __syncthreads();
        }
    }

    for (int i = threadIdx.x; i < K_DIM; i += 256) {
        unsigned int low = (unsigned int)(A[i] & 0xFFFFFFFFu);
        idx_out[b * K_DIM + i] = (int)(N_DIM - 1 - low);
    }
}

// ---------------------------------------------------------------------------
// Gather: out[b, j, :] = x[b, idx[b*K + j], :].
// One float4 per thread; each 64-lane wave covers exactly one 1 KB row.
// ---------------------------------------------------------------------------
__global__ __launch_bounds__(256)
void gather_rows_kernel(const float* __restrict__ x,
                        const int* __restrict__ idx,
                        float* __restrict__ out) {
    size_t gid = (size_t)blockIdx.x * blockDim.x + threadIdx.x; // per float4
    int f4     = (int)(gid & (F_DIM / 4 - 1));   // 0..63
    size_t row = gid >> 6;                       // b*K + j
    int b      = (int)(row >> 10);               // / K_DIM
    int src    = idx[row];                       // wave-uniform -> broadcast

    const float4* src_ptr =
        (const float4*)(x + ((size_t)b * N_DIM + (size_t)src) * F_DIM) + f4;
    ((float4*)out)[gid] = *src_ptr;
}

extern "C" void kernel_launch(void* const* d_in, const int* in_sizes, int n_in,
                              void* d_out, int out_size, void* d_ws, size_t ws_size,
                              hipStream_t stream) {
    const float* x = (const float*)d_in[0];
    float* out = (float*)d_out;

    unsigned long long* runs = (unsigned long long*)d_ws;          // 2 MB
    int* idx_ws = (int*)((char*)d_ws + (size_t)B_DIM * N_DIM * 8); // 128 KB

    sort_runs_kernel<<<B_DIM * RUNS_PER_B, 256, 0, stream>>>(x, runs);
    merge_topk_kernel<<<B_DIM, 256, 0, stream>>>(runs, idx_ws);

    const size_t total_f4 = (size_t)B_DIM * K_DIM * F_DIM / 4;  // 2,097,152
    gather_rows_kernel<<<(int)(total_f4 / 256), 256, 0, stream>>>(x, idx_ws, out);
}

// Round 3
// 343.545 us; speedup vs baseline: 1.3521x; 1.0797x over previous
//
#include <hip/hip_runtime.h>
#include <hip/hip_bf16.h>

// Problem constants (from setup_inputs): x[B=32, N=8192, F=256] fp32, k=1024.
#define B_DIM 32
#define N_DIM 8192
#define F_DIM 256
#define K_DIM 1024
#define RUNS_PER_B 8          // N / K

// Monotonic float32 -> uint32 transform (total order; inputs are normals, no NaN).
__device__ __forceinline__ unsigned int f32_ord(float v) {
    unsigned int u = __float_as_uint(v);
    return (u & 0x80000000u) ? ~u : (u | 0x80000000u);
}

// ---------------------------------------------------------------------------
// Phase 1: B*8 blocks x 512 threads. Each block sorts one 1024-row chunk of
// the key column descending in LDS (1 pair/thread/pass) and writes the run.
// Key = (ord(value) << 32) | (N-1-row): u64-desc == value-desc, ties -> lowest
// row index first (lax.top_k semantics).
// ---------------------------------------------------------------------------
__global__ __launch_bounds__(512)
void sort_runs_kernel(const float* __restrict__ x,
                      unsigned long long* __restrict__ runs) {
    __shared__ unsigned long long K[K_DIM];  // 8 KB

    const int blk = blockIdx.x;       // b * 8 + c
    const int b   = blk >> 3;
    const int c   = blk & 7;
    const float* xcol = x + (size_t)b * N_DIM * F_DIM + (F_DIM - 1);
    const int base = c * K_DIM;

    for (int i = threadIdx.x; i < K_DIM; i += 512) {
        int row = base + i;
        float v = xcol[(size_t)row * F_DIM];
        K[i] = ((unsigned long long)f32_ord(v) << 32) |
               (unsigned int)(N_DIM - 1 - row);
    }
    __syncthreads();

    // Bitonic sort (descending), exactly one pair per thread per pass.
    for (unsigned int kk = 2; kk <= K_DIM; kk <<= 1) {
        for (unsigned int jj = kk >> 1; jj > 0; jj >>= 1) {
            unsigned int p = threadIdx.x;                       // 512 pairs
            unsigned int i = ((p & ~(jj - 1)) << 1) | (p & (jj - 1));
            unsigned int j = i | jj;
            unsigned long long a  = K[i];
            unsigned long long bb = K[j];
            bool desc = ((i & kk) == 0);
            if (desc ? (a < bb) : (a > bb)) { K[i] = bb; K[j] = a; }
            __syncthreads();
        }
    }

    // Vector store: 2 consecutive u64 per thread (16 B).
    ulonglong2* dst = (ulonglong2*)(runs + (size_t)blk * K_DIM);
    const ulonglong2* src = (const ulonglong2*)K;
    dst[threadIdx.x] = src[threadIdx.x];
}

// ---------------------------------------------------------------------------
// Phase 2: one block per batch, 1024 threads, all 8 runs in 64 KB LDS.
// Tree merge (4 -> 2 -> 1 parallel pair-merges). Each pair-merge:
//   C[i] = max(A[i], B[K-1-i])  -- exact top-K multiset of A∪B, bitonic
//   then 10-pass bitonic merge -> sorted descending.
// 34 barriers total vs 78 for the sequential fold.
// ---------------------------------------------------------------------------
__global__ __launch_bounds__(1024)
void merge_topk_kernel(const unsigned long long* __restrict__ runs,
                       int* __restrict__ idx_out) {
    __shared__ unsigned long long K[N_DIM];   // 64 KB: 8 runs of 1024

    const int b = blockIdx.x;
    const ulonglong2* src = (const ulonglong2*)(runs + (size_t)b * N_DIM);
    ulonglong2* Kv = (ulonglong2*)K;
    for (unsigned int i = threadIdx.x; i < N_DIM / 2; i += 1024) Kv[i] = src[i];
    __syncthreads();

    for (int level = 0; level < 3; ++level) {
        const unsigned int m      = 4u >> level;       // pair-merges this level
        const unsigned int stride = 1024u << level;    // B-run offset from A
        const unsigned int shift  = 11 + level;        // A-run g base = g << shift

        // Max-combine: A[i] = max(A[i], B[1023-i])  (result is bitonic)
        for (unsigned int t = threadIdx.x; t < m * 1024u; t += 1024) {
            unsigned int g = t >> 10, i = t & 1023u;
            unsigned int a = g << shift;
            unsigned long long bv = K[a + stride + 1023u - i];
            if (bv > K[a + i]) K[a + i] = bv;
        }
        __syncthreads();

        // Bitonic merge (descending) on each A run, 10 passes.
        for (unsigned int jj = 512; jj > 0; jj >>= 1) {
            for (unsigned int t = threadIdx.x; t < m * 512u; t += 1024) {
                unsigned int g = t >> 9, p = t & 511u;
                unsigned int base = g << shift;
                unsigned int i = base + (((p & ~(jj - 1)) << 1) | (p & (jj - 1)));
                unsigned int j = i | jj;    // jj < run base alignment: safe
                unsigned long long a = K[i];
                unsigned long long c = K[j];
                if (a < c) { K[i] = c; K[j] = a; }
            }
            __syncthreads();
        }
    }

    for (unsigned int i = threadIdx.x; i < K_DIM; i += 1024) {
        unsigned int low = (unsigned int)(K[i] & 0xFFFFFFFFu);
        idx_out[b * K_DIM + i] = (int)(N_DIM - 1 - low);
    }
}

// ---------------------------------------------------------------------------
// Gather: out[b, j, :] = x[b, idx[b*K + j], :].
// One float4 per thread; each 64-lane wave covers exactly one 1 KB row.
// ---------------------------------------------------------------------------
__global__ __launch_bounds__(256)
void gather_rows_kernel(const float* __restrict__ x,
                        const int* __restrict__ idx,
                        float* __restrict__ out) {
    size_t gid = (size_t)blockIdx.x * blockDim.x + threadIdx.x; // per float4
    int f4     = (int)(gid & (F_DIM / 4 - 1));   // 0..63
    size_t row = gid >> 6;                       // b*K + j
    int b      = (int)(row >> 10);               // / K_DIM
    int src    = idx[row];                       // wave-uniform -> broadcast

    const float4* src_ptr =
        (const float4*)(x + ((size_t)b * N_DIM + (size_t)src) * F_DIM) + f4;
    ((float4*)out)[gid] = *src_ptr;
}

extern "C" void kernel_launch(void* const* d_in, const int* in_sizes, int n_in,
                              void* d_out, int out_size, void* d_ws, size_t ws_size,
                              hipStream_t stream) {
    const float* x = (const float*)d_in[0];
    float* out = (float*)d_out;

    unsigned long long* runs = (unsigned long long*)d_ws;          // 2 MB
    int* idx_ws = (int*)((char*)d_ws + (size_t)B_DIM * N_DIM * 8); // 128 KB

    sort_runs_kernel<<<B_DIM * RUNS_PER_B, 512, 0, stream>>>(x, runs);
    merge_topk_kernel<<<B_DIM, 1024, 0, stream>>>(runs, idx_ws);

    const size_t total_f4 = (size_t)B_DIM * K_DIM * F_DIM / 4;  // 2,097,152
    gather_rows_kernel<<<(int)(total_f4 / 256), 256, 0, stream>>>(x, idx_ws, out);
}